// Round 15
// baseline (91.392 us; speedup 1.0000x reference)
//
#include <hip/hip_runtime.h>
#include <hip/hip_bf16.h>
#include <math.h>

constexpr int N    = 8192;
constexpr int DIM  = 1024;

typedef __attribute__((ext_vector_type(8))) short bf16x8;   // 8 bf16 (4 VGPRs)
typedef __attribute__((ext_vector_type(4))) float f32x4;    // MFMA C/D

__device__ inline unsigned short f2bf(float f) {            // RN-even fp32->bf16
    unsigned u = __float_as_uint(f);
    u += 0x7fffu + ((u >> 16) & 1u);
    return (unsigned short)(u >> 16);
}
__device__ inline float bf2f(unsigned short h) {
    return __uint_as_float((unsigned)h << 16);
}
// packed fp32x2 -> bf16x2 (lo16 = a, hi16 = b); no builtin on gfx950
__device__ inline unsigned cvtpk(float a, float b) {
    unsigned r;
    asm("v_cvt_pk_bf16_f32 %0, %1, %2" : "=v"(r) : "v"(a), "v"(b));
    return r;
}
// async global->LDS, 16B per lane; dest must be wave-uniform base + lane*16
__device__ inline void gload16(const void* gsrc, void* ldst) {
    typedef __attribute__((address_space(1))) const unsigned int GU;
    typedef __attribute__((address_space(3))) unsigned int LU;
    __builtin_amdgcn_global_load_lds((GU*)gsrc, (LU*)ldst, 16, 0, 0);
}

// ---------------------------------------------------------------------------
// prep_w: transpose + split w into wT hi/lo planes [192][1024], proj B-frag
// XOR swizzle baked into k-order (verified round 7).
// ---------------------------------------------------------------------------
__global__ __launch_bounds__(256) void prep_w_kernel(
    const float* __restrict__ wq, const float* __restrict__ wk,
    const float* __restrict__ wv,
    unsigned short* __restrict__ wthi, unsigned short* __restrict__ wtlo)
{
    int idx = blockIdx.x * 256 + threadIdx.x;     // 0..196607
    int c   = idx >> 10;                          // 0..191
    int k   = idx & 1023;
    const float* wsrc = (c < 64) ? wq : (c < 128) ? wk : wv;
    float f = wsrc[(size_t)k * 64 + (c & 63)];
    unsigned short h = f2bf(f);
    int pos = c * 1024 + (k & ~63) + ((((k >> 3) & 7) ^ (c & 7)) << 3) + (k & 7);
    wthi[pos] = h;
    wtlo[pos] = f2bf(f - bf2f(h));
}

// ---------------------------------------------------------------------------
// Projection via split-bf16 MFMA (3-term) — round-10 verified (depth-2 x
// prefetch + cvt_pk writeA).
// ---------------------------------------------------------------------------
__global__ __launch_bounds__(256) void proj_kernel(
    const float* __restrict__ x,
    const unsigned short* __restrict__ wthi,
    const unsigned short* __restrict__ wtlo,
    unsigned short* __restrict__ qhi, unsigned short* __restrict__ qlo,
    unsigned short* __restrict__ khi, unsigned short* __restrict__ klo,
    unsigned short* __restrict__ vthi)
{
    __shared__ unsigned short As[2][2][4096];   // [buf][hi/lo][64r*64k]
    __shared__ unsigned short Bs[2][2][3072];   // [buf][hi/lo][48c*64k]

    const int tid  = threadIdx.x;
    const int lane = tid & 63;
    const int w    = tid >> 6;
    const int g16  = lane >> 4;
    const int i16  = lane & 15;
    const int row0 = blockIdx.x * 64;
    const int col0 = blockIdx.y * 48;

    float4 xn[2][4];
    auto loadX = [&](int t, int s) {
#pragma unroll
        for (int i = 0; i < 4; ++i) {
            int f4 = i * 256 + tid;
            xn[s][i] = *reinterpret_cast<const float4*>(
                x + (size_t)(row0 + (f4 >> 4)) * DIM + t * 64 + (f4 & 15) * 4);
        }
    };
    auto stageB = [&](int t, int buf) {
#pragma unroll
        for (int i = 0; i < 3; ++i) {
            int idx = i * 256 + tid;
            int p   = (idx >= 384) ? 1 : 0;
            int li  = idx - p * 384;
            const unsigned short* base = p ? wtlo : wthi;
            const unsigned short* src  = base + (size_t)(col0 + (li >> 3)) * 1024
                                         + t * 64 + (li & 7) * 8;
            gload16(src, (char*)&Bs[buf][p][0] + (size_t)li * 16);
        }
    };
    auto writeA = [&](int buf, int s) {
#pragma unroll
        for (int i = 0; i < 4; ++i) {
            int f4 = i * 256 + tid;
            int r = f4 >> 4, c4 = f4 & 15;
            float4 v = xn[s][i];
            unsigned h01 = cvtpk(v.x, v.y);
            unsigned h23 = cvtpk(v.z, v.w);
            float hx = __uint_as_float(h01 << 16);
            float hy = __uint_as_float(h01 & 0xffff0000u);
            float hz = __uint_as_float(h23 << 16);
            float hw = __uint_as_float(h23 & 0xffff0000u);
            uint2 uh = { h01, h23 };
            uint2 ul = { cvtpk(v.x - hx, v.y - hy), cvtpk(v.z - hz, v.w - hw) };
            int byte = r * 128 + (((c4 >> 1) ^ (r & 7)) << 4) + ((c4 & 1) << 3);
            *reinterpret_cast<uint2*>((char*)&As[buf][0][0] + byte) = uh;
            *reinterpret_cast<uint2*>((char*)&As[buf][1][0] + byte) = ul;
        }
    };

    f32x4 acc[3];
    acc[0] = acc[1] = acc[2] = (f32x4){0.f, 0.f, 0.f, 0.f};

    loadX(0, 0);
    loadX(1, 1);
    stageB(0, 0);
    writeA(0, 0);

    const int arow = w * 16 + i16;
#pragma unroll
    for (int t = 0; t < 16; ++t) {
        const int b = t & 1;
        __syncthreads();
        if (t < 15) stageB(t + 1, b ^ 1);
        if (t < 14) loadX(t + 2, b);          // depth-2: consumed end of iter t+1
        bf16x8 ah[2], al[2];
#pragma unroll
        for (int kc = 0; kc < 2; ++kc) {
            int off = arow * 128 + ((((kc << 2) | g16) ^ (arow & 7)) << 4);
            ah[kc] = *reinterpret_cast<const bf16x8*>((char*)&As[b][0][0] + off);
            al[kc] = *reinterpret_cast<const bf16x8*>((char*)&As[b][1][0] + off);
        }
#pragma unroll
        for (int ct = 0; ct < 3; ++ct) {
            const int colL = ct * 16 + i16;
#pragma unroll
            for (int kc = 0; kc < 2; ++kc) {
                int off = colL * 128 + ((((kc << 2) | g16) ^ (colL & 7)) << 4);
                bf16x8 bh = *reinterpret_cast<const bf16x8*>((char*)&Bs[b][0][0] + off);
                bf16x8 bl = *reinterpret_cast<const bf16x8*>((char*)&Bs[b][1][0] + off);
                acc[ct] = __builtin_amdgcn_mfma_f32_16x16x32_bf16(ah[kc], bh, acc[ct], 0, 0, 0);
                acc[ct] = __builtin_amdgcn_mfma_f32_16x16x32_bf16(ah[kc], bl, acc[ct], 0, 0, 0);
                acc[ct] = __builtin_amdgcn_mfma_f32_16x16x32_bf16(al[kc], bh, acc[ct], 0, 0, 0);
            }
        }
        if (t < 15) writeA(b ^ 1, b ^ 1);
    }

    const float QSCALE = 0.180336880f;   // log2(e)/8 folded into q
#pragma unroll
    for (int ct = 0; ct < 3; ++ct) {
        int cglob = col0 + ct * 16 + i16;
        int g = cglob >> 6, c64 = cglob & 63;
#pragma unroll
        for (int rr = 0; rr < 4; ++rr) {
            int row = row0 + w * 16 + 4 * g16 + rr;
            float f = acc[ct][rr];
            if (g == 0) {
                f *= QSCALE;
                unsigned short h = f2bf(f);
                qhi[(size_t)row * 64 + c64] = h;
                qlo[(size_t)row * 64 + c64] = f2bf(f - bf2f(h));
            } else if (g == 1) {
                int ci = c64 ^ ((row & 7) << 3);
                unsigned short h = f2bf(f);
                khi[(size_t)row * 64 + ci] = h;
                klo[(size_t)row * 64 + ci] = f2bf(f - bf2f(h));
            } else {
                int cg  = row >> 3;
                int cgs = (cg & ~7) | ((cg & 7) ^ (c64 & 7));
                vthi[(size_t)c64 * 8192 + cgs * 8 + (row & 7)] = f2bf(f);
            }
        }
    }
}

// ---------------------------------------------------------------------------
// Flash attention, swapped operands, 32 q-rows/wave (round-12 body) with
// SINGLE-buffered staging (40KB LDS) and ns=16 split-K: grid 1024 -> 4
// blocks/CU = 4 waves/SIMD, doubling TLP so the serial QK/SM/PV chain of one
// wave overlaps other waves' staging/VALU. No setprio (hurts lockstep, m190).
// ---------------------------------------------------------------------------
constexpr int BQ = 128;
constexpr int BK = 64;

__global__ __launch_bounds__(256) void attn_kernel(
    const unsigned short* __restrict__ qhi, const unsigned short* __restrict__ qlo,
    const unsigned short* __restrict__ khi, const unsigned short* __restrict__ klo,
    const unsigned short* __restrict__ vthi,
    float* __restrict__ po, float* __restrict__ pm, float* __restrict__ pl,
    int keys_per_split)
{
    __shared__ __align__(16) unsigned short stage[12288];      // 24KB single buf
    __shared__ __align__(16) unsigned short plds[4][2][1024];  // per-wave/set P^T

    const int tid  = threadIdx.x;
    const int lane = tid & 63;
    const int w    = tid >> 6;
    const int g16  = lane >> 4;      // 0..3
    const int i16  = lane & 15;      // q-row within set tile
    const int qrow0 = blockIdx.x * BQ;
    const int split = blockIdx.y;
    const int key0  = split * keys_per_split;
    const int nt    = keys_per_split / BK;
    const int xorm  = (i16 & 7) << 4;
    const int wbase = i16 * 128;

    // Q fragments: [set][c]; lane holds Q[q = w*32+set*16+i16][d=32c+8g16+e]
    bf16x8 qh[2][2], ql[2][2];
#pragma unroll
    for (int s = 0; s < 2; ++s) {
        const size_t qr = (size_t)(qrow0 + w * 32 + s * 16 + i16) * 64;
#pragma unroll
        for (int c = 0; c < 2; ++c) {
            qh[s][c] = *reinterpret_cast<const bf16x8*>(qhi + qr + c * 32 + g16 * 8);
            ql[s][c] = *reinterpret_cast<const bf16x8*>(qlo + qr + c * 32 + g16 * 8);
        }
    }
    bf16x8 ones;
#pragma unroll
    for (int e = 0; e < 8; ++e) ones[e] = (short)0x3F80;   // bf16 1.0

    float m[2] = {-INFINITY, -INFINITY};
    f32x4 o_acc[2][4], o5[2];
#pragma unroll
    for (int s = 0; s < 2; ++s) {
        o5[s] = {0.f, 0.f, 0.f, 0.f};
#pragma unroll
        for (int db = 0; db < 4; ++db) o_acc[s][db] = {0.f, 0.f, 0.f, 0.f};
    }

    // incremental staging pointers (advance by constant per tile)
    const int srow = tid >> 3, sch = tid & 7;
    const unsigned short* s0 = khi  + (size_t)(key0 + srow) * 64 + sch * 8;
    const unsigned short* s1 = khi  + (size_t)(key0 + 32 + srow) * 64 + sch * 8;
    const unsigned short* s2 = klo  + (size_t)(key0 + srow) * 64 + sch * 8;
    const unsigned short* s3 = klo  + (size_t)(key0 + 32 + srow) * 64 + sch * 8;
    const unsigned short* s4 = vthi + (size_t)srow * 8192 + key0 + sch * 8;
    const unsigned short* s5 = vthi + (size_t)(32 + srow) * 8192 + key0 + sch * 8;

    for (int t = 0; t < nt; ++t) {
        __syncthreads();   // all waves done reading stage from tile t-1
        {
            char* dst = (char*)stage + tid * 16;
            gload16(s0, dst);             s0 += 4096;   // 64 rows x 64 shorts
            gload16(s1, dst + 4096);      s1 += 4096;
            gload16(s2, dst + 8192);      s2 += 4096;
            gload16(s3, dst + 12288);     s3 += 4096;
            gload16(s4, dst + 16384);     s4 += 64;     // BK shorts along keys
            gload16(s5, dst + 20480);     s5 += 64;
        }
        __syncthreads();   // drains vmcnt: tile t staged
        const char* stg = (const char*)stage;

        // ---- QK^T swapped: K frags read once, used by BOTH sets ----
        f32x4 sacc[2][4];
#pragma unroll
        for (int j = 0; j < 4; ++j) {
            sacc[0][j] = {0.f, 0.f, 0.f, 0.f};
            sacc[1][j] = {0.f, 0.f, 0.f, 0.f};
            const int kr = 16 * j + i16;
#pragma unroll
            for (int c = 0; c < 2; ++c) {
                const int byteO = kr * 128 + ((c * 64 + g16 * 16) ^ ((kr & 7) << 4));
                bf16x8 kh = *reinterpret_cast<const bf16x8*>(stg + byteO);
                bf16x8 kl = *reinterpret_cast<const bf16x8*>(stg + byteO + 8192);
#pragma unroll
                for (int s = 0; s < 2; ++s) {
                    sacc[s][j] = __builtin_amdgcn_mfma_f32_16x16x32_bf16(kh, qh[s][c], sacc[s][j], 0, 0, 0);
                    sacc[s][j] = __builtin_amdgcn_mfma_f32_16x16x32_bf16(kh, ql[s][c], sacc[s][j], 0, 0, 0);
                    sacc[s][j] = __builtin_amdgcn_mfma_f32_16x16x32_bf16(kl, qh[s][c], sacc[s][j], 0, 0, 0);
                }
            }
        }

        // ---- defer-max online softmax (lane-local stats) ----
        float aloc[2];
#pragma unroll
        for (int s = 0; s < 2; ++s) {
            float a0 = fmaxf(fmaxf(sacc[s][0][0], sacc[s][0][1]), fmaxf(sacc[s][0][2], sacc[s][0][3]));
            float a1 = fmaxf(fmaxf(sacc[s][1][0], sacc[s][1][1]), fmaxf(sacc[s][1][2], sacc[s][1][3]));
            float a2 = fmaxf(fmaxf(sacc[s][2][0], sacc[s][2][1]), fmaxf(sacc[s][2][2], sacc[s][2][3]));
            float a3 = fmaxf(fmaxf(sacc[s][3][0], sacc[s][3][1]), fmaxf(sacc[s][3][2], sacc[s][3][3]));
            aloc[s] = fmaxf(fmaxf(a0, a1), fmaxf(a2, a3));
        }
        int need = (aloc[0] > m[0] + 8.f) | (aloc[1] > m[1] + 8.f);
        if (__any(need)) {
#pragma unroll
            for (int s = 0; s < 2; ++s) {
                float x2 = fmaxf(aloc[s], __shfl_xor(aloc[s], 16));
                x2 = fmaxf(x2, __shfl_xor(x2, 32));
                float mn   = fmaxf(m[s], x2);
                float corr = exp2f(m[s] - mn);     // first tile: exp2(-inf)=0
                m[s] = mn;
                o5[s] *= corr;
#pragma unroll
                for (int db = 0; db < 4; ++db) o_acc[s][db] *= corr;
            }
        }

        // ---- P = exp2(S-m), cvt_pk pack, LDS round-trip (same wave), l-MFMA ----
        bf16x8 pfrag[2][2];
#pragma unroll
        for (int s = 0; s < 2; ++s) {
            char* pb = (char*)&plds[w][s][0];
#pragma unroll
            for (int j = 0; j < 4; ++j) {
                float p0 = exp2f(sacc[s][j][0] - m[s]);
                float p1 = exp2f(sacc[s][j][1] - m[s]);
                float p2 = exp2f(sacc[s][j][2] - m[s]);
                float p3 = exp2f(sacc[s][j][3] - m[s]);
                uint2 pdw = { cvtpk(p0, p1), cvtpk(p2, p3) };
                *reinterpret_cast<uint2*>(pb + wbase + ((32 * j + 8 * g16) ^ xorm)) = pdw;
            }
#pragma unroll
            for (int c = 0; c < 2; ++c)
                pfrag[s][c] = *reinterpret_cast<const bf16x8*>(
                    pb + wbase + ((64 * c + 16 * g16) ^ xorm));
            o5[s] = __builtin_amdgcn_mfma_f32_16x16x32_bf16(ones, pfrag[s][0], o5[s], 0, 0, 0);
            o5[s] = __builtin_amdgcn_mfma_f32_16x16x32_bf16(ones, pfrag[s][1], o5[s], 0, 0, 0);
        }

        // ---- PV swapped: V frags read once, used by BOTH sets ----
#pragma unroll
        for (int db = 0; db < 4; ++db) {
            const int vr = 16 * db + i16;
#pragma unroll
            for (int c = 0; c < 2; ++c) {
                const int byteO = 16384 + vr * 128 +
                                  ((c * 64 + g16 * 16) ^ ((vr & 7) << 4));
                bf16x8 vh = *reinterpret_cast<const bf16x8*>(stg + byteO);
#pragma unroll
                for (int s = 0; s < 2; ++s)
                    o_acc[s][db] = __builtin_amdgcn_mfma_f32_16x16x32_bf16(
                                       vh, pfrag[s][c], o_acc[s][db], 0, 0, 0);
            }
        }
    }

    // epilogue: store unnormalized partials; l comes from ones-MFMA rows
#pragma unroll
    for (int s = 0; s < 2; ++s) {
        const size_t prow = (size_t)split * N + qrow0 + w * 32 + s * 16;
#pragma unroll
        for (int db = 0; db < 4; ++db) {
            float4 ov = {o_acc[s][db][0], o_acc[s][db][1],
                         o_acc[s][db][2], o_acc[s][db][3]};
            *reinterpret_cast<float4*>(po + (prow + i16) * 64 + 16 * db + 4 * g16) = ov;
        }
        if (lane < 16) {
            pm[prow + i16] = m[s];
            pl[prow + i16] = o5[s][0];
        }
    }
}

// ---------------------------------------------------------------------------
// Combine split-K partials (log2-domain maxima -> exp2f weights).
// ---------------------------------------------------------------------------
__global__ __launch_bounds__(256) void combine_kernel(
    const float* __restrict__ po,
    const float* __restrict__ pm,
    const float* __restrict__ pl,
    float* __restrict__ out, int ns)
{
    const int tid = threadIdx.x;
    const int row = blockIdx.x * 16 + (tid >> 4);
    const int c4  = tid & 15;

    float M = -INFINITY;
    for (int s = 0; s < ns; ++s)
        M = fmaxf(M, pm[(size_t)s * N + row]);
    float L = 0.f;
    float4 acc = {0.f, 0.f, 0.f, 0.f};
    for (int s = 0; s < ns; ++s) {
        float ws = exp2f(pm[(size_t)s * N + row] - M);
        L += ws * pl[(size_t)s * N + row];
        float4 ov = *reinterpret_cast<const float4*>(
            po + ((size_t)s * N + row) * 64 + c4 * 4);
        acc.x += ws * ov.x; acc.y += ws * ov.y;
        acc.z += ws * ov.z; acc.w += ws * ov.w;
    }
    float inv = 1.f / L;
    float4 res = {acc.x * inv, acc.y * inv, acc.z * inv, acc.w * inv};
    *reinterpret_cast<float4*>(out + (size_t)row * 64 + c4 * 4) = res;
}

// ---------------------------------------------------------------------------
extern "C" void kernel_launch(void* const* d_in, const int* in_sizes, int n_in,
                              void* d_out, int out_size, void* d_ws, size_t ws_size,
                              hipStream_t stream)
{
    const float* x  = (const float*)d_in[0];
    const float* wq = (const float*)d_in[1];
    const float* wk = (const float*)d_in[2];
    const float* wv = (const float*)d_in[3];
    float* out = (float*)d_out;

    const size_t PLANE = (size_t)N * 64;               // ushorts per plane
    unsigned short* qhi  = (unsigned short*)d_ws;
    unsigned short* qlo  = qhi + PLANE;
    unsigned short* khi  = qlo + PLANE;
    unsigned short* klo  = khi + PLANE;
    unsigned short* vthi = klo + PLANE;
    const size_t plane_bytes = 5 * PLANE * 2;          // 5 MB
    const size_t wt_elems = (size_t)192 * 1024;
    const size_t wt_bytes = 2 * wt_elems * 2;          // 786 KB

    int ns = 16;                                       // 1024 blocks = 4/CU
    while (ns > 1 &&
           plane_bytes + wt_bytes +
           (size_t)ns * ((size_t)N * 64 * 4 + (size_t)N * 8) > ws_size)
        ns >>= 1;

    float* po = (float*)((char*)d_ws + plane_bytes);
    float* pm = po + (size_t)ns * N * 64;
    float* pl = pm + (size_t)ns * N;
    unsigned short* wthi = (unsigned short*)(pl + (size_t)ns * N);
    unsigned short* wtlo = wthi + wt_elems;

    prep_w_kernel<<<768, 256, 0, stream>>>(wq, wk, wv, wthi, wtlo);

    dim3 pgrid(N / 64, 4);
    proj_kernel<<<pgrid, 256, 0, stream>>>(x, wthi, wtlo,
                                           qhi, qlo, khi, klo, vthi);

    dim3 agrid(N / BQ, ns);
    attn_kernel<<<agrid, 256, 0, stream>>>(qhi, qlo, khi, klo, vthi,
                                           po, pm, pl, N / ns);

    combine_kernel<<<N / 16, 256, 0, stream>>>(po, pm, pl, out, ns);
}

// Round 16
// 84.879 us; speedup vs baseline: 1.0767x; 1.0767x over previous
//
#include <hip/hip_runtime.h>
#include <hip/hip_bf16.h>
#include <math.h>

constexpr int N    = 8192;
constexpr int DIM  = 1024;

typedef __attribute__((ext_vector_type(8))) short bf16x8;   // 8 bf16 (4 VGPRs)
typedef __attribute__((ext_vector_type(4))) float f32x4;    // MFMA C/D

__device__ inline unsigned short f2bf(float f) {            // RN-even fp32->bf16
    unsigned u = __float_as_uint(f);
    u += 0x7fffu + ((u >> 16) & 1u);
    return (unsigned short)(u >> 16);
}
__device__ inline float bf2f(unsigned short h) {
    return __uint_as_float((unsigned)h << 16);
}
// packed fp32x2 -> bf16x2 (lo16 = a, hi16 = b); no builtin on gfx950
__device__ inline unsigned cvtpk(float a, float b) {
    unsigned r;
    asm("v_cvt_pk_bf16_f32 %0, %1, %2" : "=v"(r) : "v"(a), "v"(b));
    return r;
}
// async global->LDS, 16B per lane; dest must be wave-uniform base + lane*16
__device__ inline void gload16(const void* gsrc, void* ldst) {
    typedef __attribute__((address_space(1))) const unsigned int GU;
    typedef __attribute__((address_space(3))) unsigned int LU;
    __builtin_amdgcn_global_load_lds((GU*)gsrc, (LU*)ldst, 16, 0, 0);
}

// ---------------------------------------------------------------------------
// prep_w: transpose + split w into wT hi/lo planes [192][1024], proj B-frag
// XOR swizzle baked into k-order (verified round 7).
// ---------------------------------------------------------------------------
__global__ __launch_bounds__(256) void prep_w_kernel(
    const float* __restrict__ wq, const float* __restrict__ wk,
    const float* __restrict__ wv,
    unsigned short* __restrict__ wthi, unsigned short* __restrict__ wtlo)
{
    int idx = blockIdx.x * 256 + threadIdx.x;     // 0..196607
    int c   = idx >> 10;                          // 0..191
    int k   = idx & 1023;
    const float* wsrc = (c < 64) ? wq : (c < 128) ? wk : wv;
    float f = wsrc[(size_t)k * 64 + (c & 63)];
    unsigned short h = f2bf(f);
    int pos = c * 1024 + (k & ~63) + ((((k >> 3) & 7) ^ (c & 7)) << 3) + (k & 7);
    wthi[pos] = h;
    wtlo[pos] = f2bf(f - bf2f(h));
}

// ---------------------------------------------------------------------------
// Projection via split-bf16 MFMA (3-term) — round-10 verified (depth-2 x
// prefetch + cvt_pk writeA).
// ---------------------------------------------------------------------------
__global__ __launch_bounds__(256) void proj_kernel(
    const float* __restrict__ x,
    const unsigned short* __restrict__ wthi,
    const unsigned short* __restrict__ wtlo,
    unsigned short* __restrict__ qhi, unsigned short* __restrict__ qlo,
    unsigned short* __restrict__ khi, unsigned short* __restrict__ klo,
    unsigned short* __restrict__ vthi)
{
    __shared__ unsigned short As[2][2][4096];   // [buf][hi/lo][64r*64k]
    __shared__ unsigned short Bs[2][2][3072];   // [buf][hi/lo][48c*64k]

    const int tid  = threadIdx.x;
    const int lane = tid & 63;
    const int w    = tid >> 6;
    const int g16  = lane >> 4;
    const int i16  = lane & 15;
    const int row0 = blockIdx.x * 64;
    const int col0 = blockIdx.y * 48;

    float4 xn[2][4];
    auto loadX = [&](int t, int s) {
#pragma unroll
        for (int i = 0; i < 4; ++i) {
            int f4 = i * 256 + tid;
            xn[s][i] = *reinterpret_cast<const float4*>(
                x + (size_t)(row0 + (f4 >> 4)) * DIM + t * 64 + (f4 & 15) * 4);
        }
    };
    auto stageB = [&](int t, int buf) {
#pragma unroll
        for (int i = 0; i < 3; ++i) {
            int idx = i * 256 + tid;
            int p   = (idx >= 384) ? 1 : 0;
            int li  = idx - p * 384;
            const unsigned short* base = p ? wtlo : wthi;
            const unsigned short* src  = base + (size_t)(col0 + (li >> 3)) * 1024
                                         + t * 64 + (li & 7) * 8;
            gload16(src, (char*)&Bs[buf][p][0] + (size_t)li * 16);
        }
    };
    auto writeA = [&](int buf, int s) {
#pragma unroll
        for (int i = 0; i < 4; ++i) {
            int f4 = i * 256 + tid;
            int r = f4 >> 4, c4 = f4 & 15;
            float4 v = xn[s][i];
            unsigned h01 = cvtpk(v.x, v.y);
            unsigned h23 = cvtpk(v.z, v.w);
            float hx = __uint_as_float(h01 << 16);
            float hy = __uint_as_float(h01 & 0xffff0000u);
            float hz = __uint_as_float(h23 << 16);
            float hw = __uint_as_float(h23 & 0xffff0000u);
            uint2 uh = { h01, h23 };
            uint2 ul = { cvtpk(v.x - hx, v.y - hy), cvtpk(v.z - hz, v.w - hw) };
            int byte = r * 128 + (((c4 >> 1) ^ (r & 7)) << 4) + ((c4 & 1) << 3);
            *reinterpret_cast<uint2*>((char*)&As[buf][0][0] + byte) = uh;
            *reinterpret_cast<uint2*>((char*)&As[buf][1][0] + byte) = ul;
        }
    };

    f32x4 acc[3];
    acc[0] = acc[1] = acc[2] = (f32x4){0.f, 0.f, 0.f, 0.f};

    loadX(0, 0);
    loadX(1, 1);
    stageB(0, 0);
    writeA(0, 0);

    const int arow = w * 16 + i16;
#pragma unroll
    for (int t = 0; t < 16; ++t) {
        const int b = t & 1;
        __syncthreads();
        if (t < 15) stageB(t + 1, b ^ 1);
        if (t < 14) loadX(t + 2, b);          // depth-2: consumed end of iter t+1
        bf16x8 ah[2], al[2];
#pragma unroll
        for (int kc = 0; kc < 2; ++kc) {
            int off = arow * 128 + ((((kc << 2) | g16) ^ (arow & 7)) << 4);
            ah[kc] = *reinterpret_cast<const bf16x8*>((char*)&As[b][0][0] + off);
            al[kc] = *reinterpret_cast<const bf16x8*>((char*)&As[b][1][0] + off);
        }
#pragma unroll
        for (int ct = 0; ct < 3; ++ct) {
            const int colL = ct * 16 + i16;
#pragma unroll
            for (int kc = 0; kc < 2; ++kc) {
                int off = colL * 128 + ((((kc << 2) | g16) ^ (colL & 7)) << 4);
                bf16x8 bh = *reinterpret_cast<const bf16x8*>((char*)&Bs[b][0][0] + off);
                bf16x8 bl = *reinterpret_cast<const bf16x8*>((char*)&Bs[b][1][0] + off);
                acc[ct] = __builtin_amdgcn_mfma_f32_16x16x32_bf16(ah[kc], bh, acc[ct], 0, 0, 0);
                acc[ct] = __builtin_amdgcn_mfma_f32_16x16x32_bf16(ah[kc], bl, acc[ct], 0, 0, 0);
                acc[ct] = __builtin_amdgcn_mfma_f32_16x16x32_bf16(al[kc], bh, acc[ct], 0, 0, 0);
            }
        }
        if (t < 15) writeA(b ^ 1, b ^ 1);
    }

    const float QSCALE = 0.180336880f;   // log2(e)/8 folded into q
#pragma unroll
    for (int ct = 0; ct < 3; ++ct) {
        int cglob = col0 + ct * 16 + i16;
        int g = cglob >> 6, c64 = cglob & 63;
#pragma unroll
        for (int rr = 0; rr < 4; ++rr) {
            int row = row0 + w * 16 + 4 * g16 + rr;
            float f = acc[ct][rr];
            if (g == 0) {
                f *= QSCALE;
                unsigned short h = f2bf(f);
                qhi[(size_t)row * 64 + c64] = h;
                qlo[(size_t)row * 64 + c64] = f2bf(f - bf2f(h));
            } else if (g == 1) {
                int ci = c64 ^ ((row & 7) << 3);
                unsigned short h = f2bf(f);
                khi[(size_t)row * 64 + ci] = h;
                klo[(size_t)row * 64 + ci] = f2bf(f - bf2f(h));
            } else {
                int cg  = row >> 3;
                int cgs = (cg & ~7) | ((cg & 7) ^ (c64 & 7));
                vthi[(size_t)c64 * 8192 + cgs * 8 + (row & 7)] = f2bf(f);
            }
        }
    }
}

// ---------------------------------------------------------------------------
// Flash attention — round-12 config (2-set swapped operands, dbuf staging,
// defer-max, ns=8) with MFMA CHAIN INTERLEAVING: QK issued c->term->j->s
// (each sacc revisited every 8 MFMAs), PV issued c->db->s (gap 8), so MFMA
// dependency latency is hidden by ILP instead of (absent) TLP.
// ---------------------------------------------------------------------------
constexpr int BQ = 128;
constexpr int BK = 64;

__global__ __launch_bounds__(256) void attn_kernel(
    const unsigned short* __restrict__ qhi, const unsigned short* __restrict__ qlo,
    const unsigned short* __restrict__ khi, const unsigned short* __restrict__ klo,
    const unsigned short* __restrict__ vthi,
    float* __restrict__ po, float* __restrict__ pm, float* __restrict__ pl,
    int keys_per_split)
{
    __shared__ __align__(16) unsigned short stage[2][12288];   // 2 x 24KB dbuf
    __shared__ __align__(16) unsigned short plds[4][2][1024];  // per-wave/set P^T

    const int tid  = threadIdx.x;
    const int lane = tid & 63;
    const int w    = tid >> 6;
    const int g16  = lane >> 4;      // 0..3
    const int i16  = lane & 15;      // q-row within set tile
    const int qrow0 = blockIdx.x * BQ;
    const int split = blockIdx.y;
    const int key0  = split * keys_per_split;
    const int nt    = keys_per_split / BK;
    const int xorm  = (i16 & 7) << 4;
    const int wbase = i16 * 128;

    // Q fragments: [set][c]; lane holds Q[q = w*32+set*16+i16][d=32c+8g16+e]
    bf16x8 qh[2][2], ql[2][2];
#pragma unroll
    for (int s = 0; s < 2; ++s) {
        const size_t qr = (size_t)(qrow0 + w * 32 + s * 16 + i16) * 64;
#pragma unroll
        for (int c = 0; c < 2; ++c) {
            qh[s][c] = *reinterpret_cast<const bf16x8*>(qhi + qr + c * 32 + g16 * 8);
            ql[s][c] = *reinterpret_cast<const bf16x8*>(qlo + qr + c * 32 + g16 * 8);
        }
    }
    bf16x8 ones;
#pragma unroll
    for (int e = 0; e < 8; ++e) ones[e] = (short)0x3F80;   // bf16 1.0

    float m[2] = {-INFINITY, -INFINITY};
    f32x4 o_acc[2][4], o5[2];
#pragma unroll
    for (int s = 0; s < 2; ++s) {
        o5[s] = {0.f, 0.f, 0.f, 0.f};
#pragma unroll
        for (int db = 0; db < 4; ++db) o_acc[s][db] = {0.f, 0.f, 0.f, 0.f};
    }

    auto stageKV = [&](int t, int buf) {
        const int key0t = key0 + t * BK;
#pragma unroll
        for (int u = 0; u < 6; ++u) {
            int row = ((u & 1) << 5) + (tid >> 3);
            int ch  = tid & 7;
            const unsigned short* src;
            if (u < 2)      src = khi  + (size_t)(key0t + row) * 64 + ch * 8;
            else if (u < 4) src = klo  + (size_t)(key0t + row) * 64 + ch * 8;
            else            src = vthi + (size_t)row * 8192 + key0t + ch * 8;
            gload16(src, (char*)&stage[buf][0] + u * 4096 + tid * 16);
        }
    };

    stageKV(0, 0);

    for (int t = 0; t < nt; ++t) {
        const int b = t & 1;
        __syncthreads();   // drains tile-t loads; all waves done reading buf b^1
        if (t + 1 < nt) stageKV(t + 1, b ^ 1);   // in flight during compute(t)
        const char* stg = (const char*)&stage[b][0];

        // ---- QK^T swapped, chain-interleaved: c -> term -> j -> s ----
        f32x4 sacc[2][4];
#pragma unroll
        for (int j = 0; j < 4; ++j) {
            sacc[0][j] = {0.f, 0.f, 0.f, 0.f};
            sacc[1][j] = {0.f, 0.f, 0.f, 0.f};
        }
#pragma unroll
        for (int c = 0; c < 2; ++c) {
            bf16x8 kh[4], kl[4];
#pragma unroll
            for (int j = 0; j < 4; ++j) {
                const int kr = 16 * j + i16;
                const int byteO = kr * 128 + ((c * 64 + g16 * 16) ^ ((kr & 7) << 4));
                kh[j] = *reinterpret_cast<const bf16x8*>(stg + byteO);
                kl[j] = *reinterpret_cast<const bf16x8*>(stg + byteO + 8192);
            }
            // term 1: kh x qh — 8 independent MFMAs
#pragma unroll
            for (int j = 0; j < 4; ++j)
#pragma unroll
                for (int s = 0; s < 2; ++s)
                    sacc[s][j] = __builtin_amdgcn_mfma_f32_16x16x32_bf16(
                                     kh[j], qh[s][c], sacc[s][j], 0, 0, 0);
            // term 2: kh x ql — 8 independent
#pragma unroll
            for (int j = 0; j < 4; ++j)
#pragma unroll
                for (int s = 0; s < 2; ++s)
                    sacc[s][j] = __builtin_amdgcn_mfma_f32_16x16x32_bf16(
                                     kh[j], ql[s][c], sacc[s][j], 0, 0, 0);
            // term 3: kl x qh — 8 independent
#pragma unroll
            for (int j = 0; j < 4; ++j)
#pragma unroll
                for (int s = 0; s < 2; ++s)
                    sacc[s][j] = __builtin_amdgcn_mfma_f32_16x16x32_bf16(
                                     kl[j], qh[s][c], sacc[s][j], 0, 0, 0);
        }

        // ---- defer-max online softmax (lane-local stats) ----
        float aloc[2];
#pragma unroll
        for (int s = 0; s < 2; ++s) {
            float a0 = fmaxf(fmaxf(sacc[s][0][0], sacc[s][0][1]), fmaxf(sacc[s][0][2], sacc[s][0][3]));
            float a1 = fmaxf(fmaxf(sacc[s][1][0], sacc[s][1][1]), fmaxf(sacc[s][1][2], sacc[s][1][3]));
            float a2 = fmaxf(fmaxf(sacc[s][2][0], sacc[s][2][1]), fmaxf(sacc[s][2][2], sacc[s][2][3]));
            float a3 = fmaxf(fmaxf(sacc[s][3][0], sacc[s][3][1]), fmaxf(sacc[s][3][2], sacc[s][3][3]));
            aloc[s] = fmaxf(fmaxf(a0, a1), fmaxf(a2, a3));
        }
        int need = (aloc[0] > m[0] + 8.f) | (aloc[1] > m[1] + 8.f);
        if (__any(need)) {
#pragma unroll
            for (int s = 0; s < 2; ++s) {
                float x2 = fmaxf(aloc[s], __shfl_xor(aloc[s], 16));
                x2 = fmaxf(x2, __shfl_xor(x2, 32));
                float mn   = fmaxf(m[s], x2);
                float corr = exp2f(m[s] - mn);     // first tile: exp2(-inf)=0
                m[s] = mn;
                o5[s] *= corr;
#pragma unroll
                for (int db = 0; db < 4; ++db) o_acc[s][db] *= corr;
            }
        }

        // ---- P = exp2(S-m), cvt_pk pack, LDS round-trip (same wave) ----
        bf16x8 pfrag[2][2];
#pragma unroll
        for (int s = 0; s < 2; ++s) {
            char* pb = (char*)&plds[w][s][0];
#pragma unroll
            for (int j = 0; j < 4; ++j) {
                float p0 = exp2f(sacc[s][j][0] - m[s]);
                float p1 = exp2f(sacc[s][j][1] - m[s]);
                float p2 = exp2f(sacc[s][j][2] - m[s]);
                float p3 = exp2f(sacc[s][j][3] - m[s]);
                uint2 pdw = { cvtpk(p0, p1), cvtpk(p2, p3) };
                *reinterpret_cast<uint2*>(pb + wbase + ((32 * j + 8 * g16) ^ xorm)) = pdw;
            }
#pragma unroll
            for (int c = 0; c < 2; ++c)
                pfrag[s][c] = *reinterpret_cast<const bf16x8*>(
                    pb + wbase + ((64 * c + 16 * g16) ^ xorm));
        }

        // ---- PV swapped, chain-interleaved: c -> db -> s (+ l-MFMAs) ----
#pragma unroll
        for (int c = 0; c < 2; ++c) {
            bf16x8 vh[4];
#pragma unroll
            for (int db = 0; db < 4; ++db) {
                const int vr = 16 * db + i16;
                const int byteO = 16384 + vr * 128 +
                                  ((c * 64 + g16 * 16) ^ ((vr & 7) << 4));
                vh[db] = *reinterpret_cast<const bf16x8*>(stg + byteO);
            }
            // l-MFMAs first (independent of o_acc chains)
            o5[0] = __builtin_amdgcn_mfma_f32_16x16x32_bf16(ones, pfrag[0][c], o5[0], 0, 0, 0);
            o5[1] = __builtin_amdgcn_mfma_f32_16x16x32_bf16(ones, pfrag[1][c], o5[1], 0, 0, 0);
#pragma unroll
            for (int db = 0; db < 4; ++db)
#pragma unroll
                for (int s = 0; s < 2; ++s)
                    o_acc[s][db] = __builtin_amdgcn_mfma_f32_16x16x32_bf16(
                                       vh[db], pfrag[s][c], o_acc[s][db], 0, 0, 0);
        }
    }

    // epilogue: store unnormalized partials; l comes from ones-MFMA rows
#pragma unroll
    for (int s = 0; s < 2; ++s) {
        const size_t prow = (size_t)split * N + qrow0 + w * 32 + s * 16;
#pragma unroll
        for (int db = 0; db < 4; ++db) {
            float4 ov = {o_acc[s][db][0], o_acc[s][db][1],
                         o_acc[s][db][2], o_acc[s][db][3]};
            *reinterpret_cast<float4*>(po + (prow + i16) * 64 + 16 * db + 4 * g16) = ov;
        }
        if (lane < 16) {
            pm[prow + i16] = m[s];
            pl[prow + i16] = o5[s][0];
        }
    }
}

// ---------------------------------------------------------------------------
// Combine split-K partials (log2-domain maxima -> exp2f weights).
// ---------------------------------------------------------------------------
__global__ __launch_bounds__(256) void combine_kernel(
    const float* __restrict__ po,
    const float* __restrict__ pm,
    const float* __restrict__ pl,
    float* __restrict__ out, int ns)
{
    const int tid = threadIdx.x;
    const int row = blockIdx.x * 16 + (tid >> 4);
    const int c4  = tid & 15;

    float M = -INFINITY;
    for (int s = 0; s < ns; ++s)
        M = fmaxf(M, pm[(size_t)s * N + row]);
    float L = 0.f;
    float4 acc = {0.f, 0.f, 0.f, 0.f};
    for (int s = 0; s < ns; ++s) {
        float ws = exp2f(pm[(size_t)s * N + row] - M);
        L += ws * pl[(size_t)s * N + row];
        float4 ov = *reinterpret_cast<const float4*>(
            po + ((size_t)s * N + row) * 64 + c4 * 4);
        acc.x += ws * ov.x; acc.y += ws * ov.y;
        acc.z += ws * ov.z; acc.w += ws * ov.w;
    }
    float inv = 1.f / L;
    float4 res = {acc.x * inv, acc.y * inv, acc.z * inv, acc.w * inv};
    *reinterpret_cast<float4*>(out + (size_t)row * 64 + c4 * 4) = res;
}

// ---------------------------------------------------------------------------
extern "C" void kernel_launch(void* const* d_in, const int* in_sizes, int n_in,
                              void* d_out, int out_size, void* d_ws, size_t ws_size,
                              hipStream_t stream)
{
    const float* x  = (const float*)d_in[0];
    const float* wq = (const float*)d_in[1];
    const float* wk = (const float*)d_in[2];
    const float* wv = (const float*)d_in[3];
    float* out = (float*)d_out;

    const size_t PLANE = (size_t)N * 64;               // ushorts per plane
    unsigned short* qhi  = (unsigned short*)d_ws;
    unsigned short* qlo  = qhi + PLANE;
    unsigned short* khi  = qlo + PLANE;
    unsigned short* klo  = khi + PLANE;
    unsigned short* vthi = klo + PLANE;
    const size_t plane_bytes = 5 * PLANE * 2;          // 5 MB
    const size_t wt_elems = (size_t)192 * 1024;
    const size_t wt_bytes = 2 * wt_elems * 2;          // 786 KB

    int ns = 8;
    while (ns > 1 &&
           plane_bytes + wt_bytes +
           (size_t)ns * ((size_t)N * 64 * 4 + (size_t)N * 8) > ws_size)
        ns >>= 1;

    float* po = (float*)((char*)d_ws + plane_bytes);
    float* pm = po + (size_t)ns * N * 64;
    float* pl = pm + (size_t)ns * N;
    unsigned short* wthi = (unsigned short*)(pl + (size_t)ns * N);
    unsigned short* wtlo = wthi + wt_elems;

    prep_w_kernel<<<768, 256, 0, stream>>>(wq, wk, wv, wthi, wtlo);

    dim3 pgrid(N / 64, 4);
    proj_kernel<<<pgrid, 256, 0, stream>>>(x, wthi, wtlo,
                                           qhi, qlo, khi, klo, vthi);

    dim3 agrid(N / BQ, ns);
    attn_kernel<<<agrid, 256, 0, stream>>>(qhi, qlo, khi, klo, vthi,
                                           po, pm, pl, N / ns);

    combine_kernel<<<N / 16, 256, 0, stream>>>(po, pm, pl, out, ns);
}

// Round 17
// 84.340 us; speedup vs baseline: 1.0836x; 1.0064x over previous
//
#include <hip/hip_runtime.h>
#include <hip/hip_bf16.h>
#include <math.h>

constexpr int N    = 8192;
constexpr int DIM  = 1024;

typedef __attribute__((ext_vector_type(8))) short bf16x8;   // 8 bf16 (4 VGPRs)
typedef __attribute__((ext_vector_type(4))) float f32x4;    // MFMA C/D

__device__ inline unsigned short f2bf(float f) {            // RN-even fp32->bf16
    unsigned u = __float_as_uint(f);
    u += 0x7fffu + ((u >> 16) & 1u);
    return (unsigned short)(u >> 16);
}
__device__ inline float bf2f(unsigned short h) {
    return __uint_as_float((unsigned)h << 16);
}
// packed fp32x2 -> bf16x2 (lo16 = a, hi16 = b); no builtin on gfx950
__device__ inline unsigned cvtpk(float a, float b) {
    unsigned r;
    asm("v_cvt_pk_bf16_f32 %0, %1, %2" : "=v"(r) : "v"(a), "v"(b));
    return r;
}
// async global->LDS, 16B per lane; dest must be wave-uniform base + lane*16
__device__ inline void gload16(const void* gsrc, void* ldst) {
    typedef __attribute__((address_space(1))) const unsigned int GU;
    typedef __attribute__((address_space(3))) unsigned int LU;
    __builtin_amdgcn_global_load_lds((GU*)gsrc, (LU*)ldst, 16, 0, 0);
}

// ---------------------------------------------------------------------------
// prep_w: transpose + split w into wT hi/lo planes [192][1024], proj B-frag
// XOR swizzle baked into k-order (verified round 7).
// ---------------------------------------------------------------------------
__global__ __launch_bounds__(256) void prep_w_kernel(
    const float* __restrict__ wq, const float* __restrict__ wk,
    const float* __restrict__ wv,
    unsigned short* __restrict__ wthi, unsigned short* __restrict__ wtlo)
{
    int idx = blockIdx.x * 256 + threadIdx.x;     // 0..196607
    int c   = idx >> 10;                          // 0..191
    int k   = idx & 1023;
    const float* wsrc = (c < 64) ? wq : (c < 128) ? wk : wv;
    float f = wsrc[(size_t)k * 64 + (c & 63)];
    unsigned short h = f2bf(f);
    int pos = c * 1024 + (k & ~63) + ((((k >> 3) & 7) ^ (c & 7)) << 3) + (k & 7);
    wthi[pos] = h;
    wtlo[pos] = f2bf(f - bf2f(h));
}

// ---------------------------------------------------------------------------
// Projection via split-bf16 MFMA (3-term). NEW geometry for TLP: 32 rows x
// 64 cols per block, grid (256,3)=768 = 3 blocks/CU (48KB LDS each), 4 waves
// = 4 col-tiles x 2 row-tiles. Each block covers exactly one of q|k|v.
// Depth-2 x prefetch + cvt_pk conversion (round-10 verified pieces).
// ---------------------------------------------------------------------------
__global__ __launch_bounds__(256) void proj_kernel(
    const float* __restrict__ x,
    const unsigned short* __restrict__ wthi,
    const unsigned short* __restrict__ wtlo,
    unsigned short* __restrict__ qhi, unsigned short* __restrict__ qlo,
    unsigned short* __restrict__ khi, unsigned short* __restrict__ klo,
    unsigned short* __restrict__ vthi)
{
    __shared__ unsigned short As[2][2][2048];   // [buf][hi/lo][32r*64k] 4KB planes
    __shared__ unsigned short Bs[2][2][4096];   // [buf][hi/lo][64c*64k] 8KB planes

    const int tid  = threadIdx.x;
    const int lane = tid & 63;
    const int w    = tid >> 6;        // col-tile 0..3
    const int g16  = lane >> 4;
    const int i16  = lane & 15;
    const int row0 = blockIdx.x * 32;
    const int col0 = blockIdx.y * 64;

    float4 xn[2][2];
    auto loadX = [&](int t, int s) {
#pragma unroll
        for (int i = 0; i < 2; ++i) {
            int f4 = i * 256 + tid;           // 0..511
            xn[s][i] = *reinterpret_cast<const float4*>(
                x + (size_t)(row0 + (f4 >> 4)) * DIM + t * 64 + (f4 & 15) * 4);
        }
    };
    auto stageB = [&](int t, int buf) {
#pragma unroll
        for (int i = 0; i < 4; ++i) {
            int idx = i * 256 + tid;          // 0..1023
            int p   = idx >> 9;               // plane (512 chunks each)
            int li  = idx & 511;
            const unsigned short* base = p ? wtlo : wthi;
            const unsigned short* src  = base + (size_t)(col0 + (li >> 3)) * 1024
                                         + t * 64 + (li & 7) * 8;
            gload16(src, (char*)&Bs[buf][p][0] + (size_t)li * 16);
        }
    };
    auto writeA = [&](int buf, int s) {
#pragma unroll
        for (int i = 0; i < 2; ++i) {
            int f4 = i * 256 + tid;
            int r = f4 >> 4, c4 = f4 & 15;
            float4 v = xn[s][i];
            unsigned h01 = cvtpk(v.x, v.y);
            unsigned h23 = cvtpk(v.z, v.w);
            float hx = __uint_as_float(h01 << 16);
            float hy = __uint_as_float(h01 & 0xffff0000u);
            float hz = __uint_as_float(h23 << 16);
            float hw = __uint_as_float(h23 & 0xffff0000u);
            uint2 uh = { h01, h23 };
            uint2 ul = { cvtpk(v.x - hx, v.y - hy), cvtpk(v.z - hz, v.w - hw) };
            int byte = r * 128 + (((c4 >> 1) ^ (r & 7)) << 4) + ((c4 & 1) << 3);
            *reinterpret_cast<uint2*>((char*)&As[buf][0][0] + byte) = uh;
            *reinterpret_cast<uint2*>((char*)&As[buf][1][0] + byte) = ul;
        }
    };

    f32x4 acc[2];
    acc[0] = acc[1] = (f32x4){0.f, 0.f, 0.f, 0.f};

    loadX(0, 0);
    loadX(1, 1);
    stageB(0, 0);
    writeA(0, 0);

    const int colL = w * 16 + i16;
#pragma unroll
    for (int t = 0; t < 16; ++t) {
        const int b = t & 1;
        __syncthreads();
        if (t < 15) stageB(t + 1, b ^ 1);
        if (t < 14) loadX(t + 2, b);          // depth-2: consumed end of iter t+1
        bf16x8 ah[2][2], al[2][2];            // [rt][kc]
#pragma unroll
        for (int rt = 0; rt < 2; ++rt)
#pragma unroll
            for (int kc = 0; kc < 2; ++kc) {
                int arow = rt * 16 + i16;
                int off = arow * 128 + ((((kc << 2) | g16) ^ (arow & 7)) << 4);
                ah[rt][kc] = *reinterpret_cast<const bf16x8*>((char*)&As[b][0][0] + off);
                al[rt][kc] = *reinterpret_cast<const bf16x8*>((char*)&As[b][1][0] + off);
            }
#pragma unroll
        for (int kc = 0; kc < 2; ++kc) {
            int off = colL * 128 + ((((kc << 2) | g16) ^ (colL & 7)) << 4);
            bf16x8 bh = *reinterpret_cast<const bf16x8*>((char*)&Bs[b][0][0] + off);
            bf16x8 bl = *reinterpret_cast<const bf16x8*>((char*)&Bs[b][1][0] + off);
            // term-major: acc[rt] revisited at gap 2
#pragma unroll
            for (int rt = 0; rt < 2; ++rt)
                acc[rt] = __builtin_amdgcn_mfma_f32_16x16x32_bf16(ah[rt][kc], bh, acc[rt], 0, 0, 0);
#pragma unroll
            for (int rt = 0; rt < 2; ++rt)
                acc[rt] = __builtin_amdgcn_mfma_f32_16x16x32_bf16(ah[rt][kc], bl, acc[rt], 0, 0, 0);
#pragma unroll
            for (int rt = 0; rt < 2; ++rt)
                acc[rt] = __builtin_amdgcn_mfma_f32_16x16x32_bf16(al[rt][kc], bh, acc[rt], 0, 0, 0);
        }
        if (t < 15) writeA(b ^ 1, b ^ 1);
    }

    // epilogue: attn-ready planes; block-uniform g (col0 selects q|k|v)
    const float QSCALE = 0.180336880f;   // log2(e)/8 folded into q
    const int cglob = col0 + w * 16 + i16;
    const int g = cglob >> 6, c64 = cglob & 63;
#pragma unroll
    for (int rt = 0; rt < 2; ++rt)
#pragma unroll
        for (int rr = 0; rr < 4; ++rr) {
            int row = row0 + rt * 16 + 4 * g16 + rr;
            float f = acc[rt][rr];
            if (g == 0) {
                f *= QSCALE;
                unsigned short h = f2bf(f);
                qhi[(size_t)row * 64 + c64] = h;
                qlo[(size_t)row * 64 + c64] = f2bf(f - bf2f(h));
            } else if (g == 1) {
                int ci = c64 ^ ((row & 7) << 3);
                unsigned short h = f2bf(f);
                khi[(size_t)row * 64 + ci] = h;
                klo[(size_t)row * 64 + ci] = f2bf(f - bf2f(h));
            } else {
                int cg  = row >> 3;
                int cgs = (cg & ~7) | ((cg & 7) ^ (c64 & 7));
                vthi[(size_t)c64 * 8192 + cgs * 8 + (row & 7)] = f2bf(f);
            }
        }
}

// ---------------------------------------------------------------------------
// Flash attention — round-16 final (2-set swapped operands, dbuf staging,
// defer-max, ns=8, MFMA chain interleaving). Measured 57.0-57.4 us.
// ---------------------------------------------------------------------------
constexpr int BQ = 128;
constexpr int BK = 64;

__global__ __launch_bounds__(256) void attn_kernel(
    const unsigned short* __restrict__ qhi, const unsigned short* __restrict__ qlo,
    const unsigned short* __restrict__ khi, const unsigned short* __restrict__ klo,
    const unsigned short* __restrict__ vthi,
    float* __restrict__ po, float* __restrict__ pm, float* __restrict__ pl,
    int keys_per_split)
{
    __shared__ __align__(16) unsigned short stage[2][12288];   // 2 x 24KB dbuf
    __shared__ __align__(16) unsigned short plds[4][2][1024];  // per-wave/set P^T

    const int tid  = threadIdx.x;
    const int lane = tid & 63;
    const int w    = tid >> 6;
    const int g16  = lane >> 4;      // 0..3
    const int i16  = lane & 15;      // q-row within set tile
    const int qrow0 = blockIdx.x * BQ;
    const int split = blockIdx.y;
    const int key0  = split * keys_per_split;
    const int nt    = keys_per_split / BK;
    const int xorm  = (i16 & 7) << 4;
    const int wbase = i16 * 128;

    // Q fragments: [set][c]; lane holds Q[q = w*32+set*16+i16][d=32c+8g16+e]
    bf16x8 qh[2][2], ql[2][2];
#pragma unroll
    for (int s = 0; s < 2; ++s) {
        const size_t qr = (size_t)(qrow0 + w * 32 + s * 16 + i16) * 64;
#pragma unroll
        for (int c = 0; c < 2; ++c) {
            qh[s][c] = *reinterpret_cast<const bf16x8*>(qhi + qr + c * 32 + g16 * 8);
            ql[s][c] = *reinterpret_cast<const bf16x8*>(qlo + qr + c * 32 + g16 * 8);
        }
    }
    bf16x8 ones;
#pragma unroll
    for (int e = 0; e < 8; ++e) ones[e] = (short)0x3F80;   // bf16 1.0

    float m[2] = {-INFINITY, -INFINITY};
    f32x4 o_acc[2][4], o5[2];
#pragma unroll
    for (int s = 0; s < 2; ++s) {
        o5[s] = {0.f, 0.f, 0.f, 0.f};
#pragma unroll
        for (int db = 0; db < 4; ++db) o_acc[s][db] = {0.f, 0.f, 0.f, 0.f};
    }

    auto stageKV = [&](int t, int buf) {
        const int key0t = key0 + t * BK;
#pragma unroll
        for (int u = 0; u < 6; ++u) {
            int row = ((u & 1) << 5) + (tid >> 3);
            int ch  = tid & 7;
            const unsigned short* src;
            if (u < 2)      src = khi  + (size_t)(key0t + row) * 64 + ch * 8;
            else if (u < 4) src = klo  + (size_t)(key0t + row) * 64 + ch * 8;
            else            src = vthi + (size_t)row * 8192 + key0t + ch * 8;
            gload16(src, (char*)&stage[buf][0] + u * 4096 + tid * 16);
        }
    };

    stageKV(0, 0);

    for (int t = 0; t < nt; ++t) {
        const int b = t & 1;
        __syncthreads();   // drains tile-t loads; all waves done reading buf b^1
        if (t + 1 < nt) stageKV(t + 1, b ^ 1);   // in flight during compute(t)
        const char* stg = (const char*)&stage[b][0];

        // ---- QK^T swapped, chain-interleaved: c -> term -> j -> s ----
        f32x4 sacc[2][4];
#pragma unroll
        for (int j = 0; j < 4; ++j) {
            sacc[0][j] = {0.f, 0.f, 0.f, 0.f};
            sacc[1][j] = {0.f, 0.f, 0.f, 0.f};
        }
#pragma unroll
        for (int c = 0; c < 2; ++c) {
            bf16x8 kh[4], kl[4];
#pragma unroll
            for (int j = 0; j < 4; ++j) {
                const int kr = 16 * j + i16;
                const int byteO = kr * 128 + ((c * 64 + g16 * 16) ^ ((kr & 7) << 4));
                kh[j] = *reinterpret_cast<const bf16x8*>(stg + byteO);
                kl[j] = *reinterpret_cast<const bf16x8*>(stg + byteO + 8192);
            }
#pragma unroll
            for (int j = 0; j < 4; ++j)
#pragma unroll
                for (int s = 0; s < 2; ++s)
                    sacc[s][j] = __builtin_amdgcn_mfma_f32_16x16x32_bf16(
                                     kh[j], qh[s][c], sacc[s][j], 0, 0, 0);
#pragma unroll
            for (int j = 0; j < 4; ++j)
#pragma unroll
                for (int s = 0; s < 2; ++s)
                    sacc[s][j] = __builtin_amdgcn_mfma_f32_16x16x32_bf16(
                                     kh[j], ql[s][c], sacc[s][j], 0, 0, 0);
#pragma unroll
            for (int j = 0; j < 4; ++j)
#pragma unroll
                for (int s = 0; s < 2; ++s)
                    sacc[s][j] = __builtin_amdgcn_mfma_f32_16x16x32_bf16(
                                     kl[j], qh[s][c], sacc[s][j], 0, 0, 0);
        }

        // ---- defer-max online softmax (lane-local stats) ----
        float aloc[2];
#pragma unroll
        for (int s = 0; s < 2; ++s) {
            float a0 = fmaxf(fmaxf(sacc[s][0][0], sacc[s][0][1]), fmaxf(sacc[s][0][2], sacc[s][0][3]));
            float a1 = fmaxf(fmaxf(sacc[s][1][0], sacc[s][1][1]), fmaxf(sacc[s][1][2], sacc[s][1][3]));
            float a2 = fmaxf(fmaxf(sacc[s][2][0], sacc[s][2][1]), fmaxf(sacc[s][2][2], sacc[s][2][3]));
            float a3 = fmaxf(fmaxf(sacc[s][3][0], sacc[s][3][1]), fmaxf(sacc[s][3][2], sacc[s][3][3]));
            aloc[s] = fmaxf(fmaxf(a0, a1), fmaxf(a2, a3));
        }
        int need = (aloc[0] > m[0] + 8.f) | (aloc[1] > m[1] + 8.f);
        if (__any(need)) {
#pragma unroll
            for (int s = 0; s < 2; ++s) {
                float x2 = fmaxf(aloc[s], __shfl_xor(aloc[s], 16));
                x2 = fmaxf(x2, __shfl_xor(x2, 32));
                float mn   = fmaxf(m[s], x2);
                float corr = exp2f(m[s] - mn);     // first tile: exp2(-inf)=0
                m[s] = mn;
                o5[s] *= corr;
#pragma unroll
                for (int db = 0; db < 4; ++db) o_acc[s][db] *= corr;
            }
        }

        // ---- P = exp2(S-m), cvt_pk pack, LDS round-trip (same wave) ----
        bf16x8 pfrag[2][2];
#pragma unroll
        for (int s = 0; s < 2; ++s) {
            char* pb = (char*)&plds[w][s][0];
#pragma unroll
            for (int j = 0; j < 4; ++j) {
                float p0 = exp2f(sacc[s][j][0] - m[s]);
                float p1 = exp2f(sacc[s][j][1] - m[s]);
                float p2 = exp2f(sacc[s][j][2] - m[s]);
                float p3 = exp2f(sacc[s][j][3] - m[s]);
                uint2 pdw = { cvtpk(p0, p1), cvtpk(p2, p3) };
                *reinterpret_cast<uint2*>(pb + wbase + ((32 * j + 8 * g16) ^ xorm)) = pdw;
            }
#pragma unroll
            for (int c = 0; c < 2; ++c)
                pfrag[s][c] = *reinterpret_cast<const bf16x8*>(
                    pb + wbase + ((64 * c + 16 * g16) ^ xorm));
        }

        // ---- PV swapped, chain-interleaved: c -> db -> s (+ l-MFMAs) ----
#pragma unroll
        for (int c = 0; c < 2; ++c) {
            bf16x8 vh[4];
#pragma unroll
            for (int db = 0; db < 4; ++db) {
                const int vr = 16 * db + i16;
                const int byteO = 16384 + vr * 128 +
                                  ((c * 64 + g16 * 16) ^ ((vr & 7) << 4));
                vh[db] = *reinterpret_cast<const bf16x8*>(stg + byteO);
            }
            o5[0] = __builtin_amdgcn_mfma_f32_16x16x32_bf16(ones, pfrag[0][c], o5[0], 0, 0, 0);
            o5[1] = __builtin_amdgcn_mfma_f32_16x16x32_bf16(ones, pfrag[1][c], o5[1], 0, 0, 0);
#pragma unroll
            for (int db = 0; db < 4; ++db)
#pragma unroll
                for (int s = 0; s < 2; ++s)
                    o_acc[s][db] = __builtin_amdgcn_mfma_f32_16x16x32_bf16(
                                       vh[db], pfrag[s][c], o_acc[s][db], 0, 0, 0);
        }
    }

    // epilogue: store unnormalized partials; l comes from ones-MFMA rows
#pragma unroll
    for (int s = 0; s < 2; ++s) {
        const size_t prow = (size_t)split * N + qrow0 + w * 32 + s * 16;
#pragma unroll
        for (int db = 0; db < 4; ++db) {
            float4 ov = {o_acc[s][db][0], o_acc[s][db][1],
                         o_acc[s][db][2], o_acc[s][db][3]};
            *reinterpret_cast<float4*>(po + (prow + i16) * 64 + 16 * db + 4 * g16) = ov;
        }
        if (lane < 16) {
            pm[prow + i16] = m[s];
            pl[prow + i16] = o5[s][0];
        }
    }
}

// ---------------------------------------------------------------------------
// Combine split-K partials (log2-domain maxima -> exp2f weights).
// ---------------------------------------------------------------------------
__global__ __launch_bounds__(256) void combine_kernel(
    const float* __restrict__ po,
    const float* __restrict__ pm,
    const float* __restrict__ pl,
    float* __restrict__ out, int ns)
{
    const int tid = threadIdx.x;
    const int row = blockIdx.x * 16 + (tid >> 4);
    const int c4  = tid & 15;

    float M = -INFINITY;
    for (int s = 0; s < ns; ++s)
        M = fmaxf(M, pm[(size_t)s * N + row]);
    float L = 0.f;
    float4 acc = {0.f, 0.f, 0.f, 0.f};
    for (int s = 0; s < ns; ++s) {
        float ws = exp2f(pm[(size_t)s * N + row] - M);
        L += ws * pl[(size_t)s * N + row];
        float4 ov = *reinterpret_cast<const float4*>(
            po + ((size_t)s * N + row) * 64 + c4 * 4);
        acc.x += ws * ov.x; acc.y += ws * ov.y;
        acc.z += ws * ov.z; acc.w += ws * ov.w;
    }
    float inv = 1.f / L;
    float4 res = {acc.x * inv, acc.y * inv, acc.z * inv, acc.w * inv};
    *reinterpret_cast<float4*>(out + (size_t)row * 64 + c4 * 4) = res;
}

// ---------------------------------------------------------------------------
extern "C" void kernel_launch(void* const* d_in, const int* in_sizes, int n_in,
                              void* d_out, int out_size, void* d_ws, size_t ws_size,
                              hipStream_t stream)
{
    const float* x  = (const float*)d_in[0];
    const float* wq = (const float*)d_in[1];
    const float* wk = (const float*)d_in[2];
    const float* wv = (const float*)d_in[3];
    float* out = (float*)d_out;

    const size_t PLANE = (size_t)N * 64;               // ushorts per plane
    unsigned short* qhi  = (unsigned short*)d_ws;
    unsigned short* qlo  = qhi + PLANE;
    unsigned short* khi  = qlo + PLANE;
    unsigned short* klo  = khi + PLANE;
    unsigned short* vthi = klo + PLANE;
    const size_t plane_bytes = 5 * PLANE * 2;          // 5 MB
    const size_t wt_elems = (size_t)192 * 1024;
    const size_t wt_bytes = 2 * wt_elems * 2;          // 786 KB

    int ns = 8;
    while (ns > 1 &&
           plane_bytes + wt_bytes +
           (size_t)ns * ((size_t)N * 64 * 4 + (size_t)N * 8) > ws_size)
        ns >>= 1;

    float* po = (float*)((char*)d_ws + plane_bytes);
    float* pm = po + (size_t)ns * N * 64;
    float* pl = pm + (size_t)ns * N;
    unsigned short* wthi = (unsigned short*)(pl + (size_t)ns * N);
    unsigned short* wtlo = wthi + wt_elems;

    prep_w_kernel<<<768, 256, 0, stream>>>(wq, wk, wv, wthi, wtlo);

    dim3 pgrid(N / 32, 3);
    proj_kernel<<<pgrid, 256, 0, stream>>>(x, wthi, wtlo,
                                           qhi, qlo, khi, klo, vthi);

    dim3 agrid(N / BQ, ns);
    attn_kernel<<<agrid, 256, 0, stream>>>(qhi, qlo, khi, klo, vthi,
                                           po, pm, pl, N / ns);

    combine_kernel<<<N / 16, 256, 0, stream>>>(po, pm, pl, out, ns);
}